// Round 14
// baseline (379.075 us; speedup 1.0000x reference)
//
#include <hip/hip_runtime.h>
#include <hip/hip_bf16.h>

typedef __hip_bfloat16 bf16;
typedef __attribute__((ext_vector_type(8))) short short8;
typedef __attribute__((ext_vector_type(4))) float floatx4;
typedef __attribute__((ext_vector_type(4))) short shortx4;

static constexpr int BATCH = 4;
static constexpr int CH    = 512;   // C
static constexpr int SEQ   = 4096;  // H*W
static constexpr int DM    = 512;   // model dim

__device__ __forceinline__ void gload16(const void* g, void* l) {
  __builtin_amdgcn_global_load_lds(
      (const __attribute__((address_space(1))) unsigned int*)g,
      (__attribute__((address_space(3))) unsigned int*)l,
      16, 0, 0);
}

// 2^x via the hardware transcendental (avoids glibc __exp2f macro collision)
__device__ __forceinline__ float hw_exp2(float x) {
  float r;
  asm("v_exp_f32 %0, %1" : "=v"(r) : "v"(x));
  return r;
}

// ---------------------------------------------------------------------------
// Weight fp32 -> bf16 conversion (4 matrices of 512x512)
// ---------------------------------------------------------------------------
__global__ __launch_bounds__(256) void cvt_weights(
    const float* __restrict__ w0, const float* __restrict__ w1,
    const float* __restrict__ w2, const float* __restrict__ w3,
    bf16* __restrict__ out) {
  const float* src = (blockIdx.y == 0) ? w0 : (blockIdx.y == 1) ? w1
                   : (blockIdx.y == 2) ? w2 : w3;
  int idx = blockIdx.x * 256 + threadIdx.x;
  out[(long)blockIdx.y * (DM * CH) + idx] = __float2bfloat16(src[idx]);
}

// ---------------------------------------------------------------------------
// x (b,c,s) fp32 -> xT (b,s,c) bf16, 64x64 LDS tiles
// ---------------------------------------------------------------------------
__global__ __launch_bounds__(256) void transpose_cvt(
    const float* __restrict__ x, bf16* __restrict__ xT) {
  __shared__ float tile[64][65];
  const int s0 = blockIdx.x * 64, c0 = blockIdx.y * 64;
  const float* xb = x + (long)blockIdx.z * CH * SEQ;
  bf16* xTb = xT + (long)blockIdx.z * SEQ * CH;
  const int t = threadIdx.x;
  const int sl = t & 63, cq = t >> 6;
  #pragma unroll
  for (int i = 0; i < 16; ++i) {
    int cl = cq * 16 + i;
    tile[cl][sl] = xb[(long)(c0 + cl) * SEQ + s0 + sl];
  }
  __syncthreads();
  const int cl2 = t & 63, sq = t >> 6;
  #pragma unroll
  for (int i = 0; i < 16; ++i) {
    int sl2 = sq * 16 + i;
    xTb[(long)(s0 + sl2) * CH + c0 + cl2] = __float2bfloat16(tile[cl2][sl2]);
  }
}

// ---------------------------------------------------------------------------
// proj128: 128x128 tile BT-GEMM for the K=512 projections. 256 threads,
// 4 waves (2x2, per-wave 64x64), BK=64, double-buffered, 64 KB LDS ->
// 2 blocks/CU (cross-block overlap hides the per-tile drain).
// KIND 0: QKV fused. grid.z = mat*4+batch (12). mat 0/1 -> bf16 row-major
//   [s][d] + bias; mat 2 -> bf16 transposed [d][s] + bias.
// KIND 1: out-proj. grid.z = batch (4). fp32 transposed [c][s] + bias.
// ---------------------------------------------------------------------------
template <int KIND>
__global__ __launch_bounds__(256, 2) void proj128(
    const bf16* __restrict__ A0, const bf16* __restrict__ Wbase,
    const float* __restrict__ b0, const float* __restrict__ b1,
    const float* __restrict__ b2, void* __restrict__ Cbase) {
  __shared__ __align__(16) bf16 As[2][128 * 64];
  __shared__ __align__(16) bf16 Bs[2][128 * 64];

  int id = blockIdx.x + gridDim.x * (blockIdx.y + gridDim.y * blockIdx.z);
  int nwg = gridDim.x * gridDim.y * gridDim.z;
  int sid = ((nwg & 7) == 0) ? ((id & 7) * (nwg >> 3) + (id >> 3)) : id;
  const int bx = sid % gridDim.x;
  const int by = (sid / gridDim.x) % gridDim.y;
  const int z  = sid / (gridDim.x * gridDim.y);
  const int mat = (KIND == 0) ? (z >> 2) : 0;
  const int bz  = (KIND == 0) ? (z & 3) : z;

  const long XSZ = (long)SEQ * CH;
  const long lK = CH;
  const bf16* Ab = A0 + (long)bz * XSZ + (long)by * 128 * lK;
  const bf16* Bb = Wbase + (long)mat * ((long)DM * CH) + (long)bx * 128 * lK;
  const float* bias = (KIND == 1) ? b0 : (mat == 0 ? b0 : mat == 1 ? b1 : b2);

  const int tid = threadIdx.x;
  const int w = tid >> 6, lane = tid & 63;
  const int wr = w >> 1, wc = w & 1;          // 2 x 2 wave grid
  const int l16 = lane & 15, quad = lane >> 4;
  const int srow = tid >> 3;                  // 0..31
  const int sp = tid & 7;
  const int slog = (sp ^ (srow & 7)) << 3;    // pre-swizzled source column
  const int pA0 = (quad ^ (l16 & 7)) << 3;
  const int pA1 = pA0 ^ 32;

  auto stageA = [&](int buf, int kt) {
    const bf16* s = Ab + kt * 64 + (long)srow * lK + slog;
    char* d = (char*)(&As[buf][0]) + tid * 16;
    #pragma unroll
    for (int r = 0; r < 4; ++r)
      gload16(s + (long)(r * 32) * lK, d + r * 4096);
  };
  auto stageB = [&](int buf, int kt) {
    const bf16* s = Bb + kt * 64 + (long)srow * lK + slog;
    char* d = (char*)(&Bs[buf][0]) + tid * 16;
    #pragma unroll
    for (int r = 0; r < 4; ++r)
      gload16(s + (long)(r * 32) * lK, d + r * 4096);
  };

  floatx4 acc[4][4];
  #pragma unroll
  for (int m = 0; m < 4; ++m)
    #pragma unroll
    for (int n = 0; n < 4; ++n) acc[m][n] = (floatx4)(0.0f);

  const int nk = CH >> 6;  // 8
  stageA(0, 0); stageB(0, 0);
  __syncthreads();

  for (int t = 0; t < nk; ++t) {
    const int cur = t & 1, nxt = cur ^ 1;
    const bool more = (t + 1 < nk);
    #pragma unroll
    for (int kc = 0; kc < 2; ++kc) {
      const int poff = kc ? pA1 : pA0;
      short8 a[4], b[4];
      #pragma unroll
      for (int i = 0; i < 4; ++i)
        a[i] = *(const short8*)(&As[cur][0] + (wr * 64 + i * 16 + l16) * 64 + poff);
      #pragma unroll
      for (int j = 0; j < 4; ++j)
        b[j] = *(const short8*)(&Bs[cur][0] + (wc * 64 + j * 16 + l16) * 64 + poff);
      if (more) {
        if (kc == 0) stageA(nxt, t + 1);
        else         stageB(nxt, t + 1);
      }
      __builtin_amdgcn_s_setprio(1);
      #pragma unroll
      for (int i = 0; i < 4; ++i)
        #pragma unroll
        for (int j = 0; j < 4; ++j)
          acc[i][j] = __builtin_amdgcn_mfma_f32_16x16x32_bf16(
              a[i], b[j], acc[i][j], 0, 0, 0);
      __builtin_amdgcn_s_setprio(0);
    }
    __syncthreads();  // drains vm+lgkm; buffer swap safe
  }

  const int rbase = by * 128 + wr * 64 + quad * 4;
  const int cbase = bx * 128 + wc * 64 + l16;
  #pragma unroll
  for (int m = 0; m < 4; ++m) {
    const int row = rbase + m * 16;
    #pragma unroll
    for (int n = 0; n < 4; ++n) {
      const int col = cbase + n * 16;
      floatx4 v = acc[m][n];
      const float bb = bias[col];
      if constexpr (KIND == 0) {
        if (mat < 2) {
          bf16* C = (bf16*)Cbase + (long)mat * (BATCH * XSZ) + (long)bz * XSZ;
          #pragma unroll
          for (int r = 0; r < 4; ++r)
            C[(long)(row + r) * DM + col] = __float2bfloat16(v[r] + bb);
        } else {
          bf16* C = (bf16*)Cbase + 2 * (BATCH * XSZ) + (long)bz * XSZ;
          alignas(8) bf16 tmp[4];
          #pragma unroll
          for (int r = 0; r < 4; ++r) tmp[r] = __float2bfloat16(v[r] + bb);
          *(shortx4*)(C + (long)col * SEQ + row) = *(const shortx4*)tmp;
        }
      } else {
        float* C = (float*)Cbase + (long)bz * XSZ;
        floatx4 o_;
        #pragma unroll
        for (int r = 0; r < 4; ++r) o_[r] = v[r] + bb;
        *(floatx4*)(C + (long)col * SEQ + row) = o_;
      }
    }
  }
}

// ---------------------------------------------------------------------------
// gemm_qk: 256x256 tile QK^T. Output PRE-SCALED by scale*log2(e) so the
// downstream softmax uses exp2 directly.
// ---------------------------------------------------------------------------
__global__ __launch_bounds__(512, 2) void gemm_qk(
    const bf16* __restrict__ A, long sAz,
    const bf16* __restrict__ B, long sBz,
    bf16* __restrict__ C, long sCz,
    float scale, int K, int ldc) {
  __shared__ __align__(16) bf16 As[2][256 * 64];
  __shared__ __align__(16) bf16 Bs[2][256 * 64];

  int id = blockIdx.x + gridDim.x * (blockIdx.y + gridDim.y * blockIdx.z);
  int nwg = gridDim.x * gridDim.y * gridDim.z;
  int sid = ((nwg & 7) == 0) ? ((id & 7) * (nwg >> 3) + (id >> 3)) : id;
  const int bx = sid % gridDim.x;
  const int by = (sid / gridDim.x) % gridDim.y;
  const int bz = sid / (gridDim.x * gridDim.y);

  const int tid = threadIdx.x;
  const long lK = K;
  const bf16* Ab = A + (long)bz * sAz + (long)by * 256 * lK;
  const bf16* Bb = B + (long)bz * sBz + (long)bx * 256 * lK;

  const int w = tid >> 6, lane = tid & 63;
  const int wr = w >> 2, wc = w & 3;          // 2 x 4 wave grid
  const int l16 = lane & 15, quad = lane >> 4;

  const int srow = tid >> 3;                  // 0..63
  const int sp = tid & 7;                     // physical 16B slot
  const int slog = (sp ^ (srow & 7)) << 3;    // pre-swizzled source column

  const int pA0 = (quad ^ (l16 & 7)) << 3;
  const int pA1 = pA0 ^ 32;

  auto stage_half = [&](const bf16* Gb, bf16* Lb, int kt, int h) {
    #pragma unroll
    for (int r = 0; r < 2; ++r) {
      const int row = h * 128 + r * 64 + srow;
      gload16(Gb + (long)kt * 64 + (long)row * lK + slog,
              (char*)Lb + row * 128 + sp * 16);
    }
  };

  floatx4 acc[8][4];
  #pragma unroll
  for (int m = 0; m < 8; ++m)
    #pragma unroll
    for (int n = 0; n < 4; ++n) acc[m][n] = (floatx4)(0.0f);

  const int nk = K >> 6;  // even
  stage_half(Ab, &As[0][0], 0, 0); stage_half(Bb, &Bs[0][0], 0, 0);
  stage_half(Ab, &As[0][0], 0, 1); stage_half(Bb, &Bs[0][0], 0, 1);
  if (nk > 1) { stage_half(Ab, &As[1][0], 1, 0); stage_half(Bb, &Bs[1][0], 1, 0); }
  asm volatile("s_waitcnt vmcnt(4)" ::: "memory");
  __builtin_amdgcn_s_barrier();

  for (int tt = 0; tt < nk; tt += 2) {
    #pragma unroll
    for (int u = 0; u < 2; ++u) {
      const bf16* __restrict__ Al = &As[u][0];
      const bf16* __restrict__ Bl = &Bs[u][0];
      short8 a[2][4], b[2][2][2];
      #pragma unroll
      for (int p = 0; p < 4; ++p) {
        const int rm = p >> 1, cn = p & 1;
        if (cn == 0) {
          #pragma unroll
          for (int kc = 0; kc < 2; ++kc)
            #pragma unroll
            for (int i = 0; i < 4; ++i)
              a[kc][i] = *(const short8*)(
                  Al + (rm * 128 + wr * 64 + i * 16 + l16) * 64
                     + (kc ? pA1 : pA0));
        }
        if (rm == 0) {
          #pragma unroll
          for (int kc = 0; kc < 2; ++kc)
            #pragma unroll
            for (int j = 0; j < 2; ++j)
              b[kc][cn][j] = *(const short8*)(
                  Bl + (cn * 128 + wc * 32 + j * 16 + l16) * 64
                     + (kc ? pA1 : pA0));
        }
        {
          const int g = u * 4 + p;
          const int stile = tt + 1 + ((g + 2) >> 2);
          if (stile < nk) {
            const int sh = (p < 2) ? 1 : 0;
            if (p & 1) stage_half(Bb, &Bs[stile & 1][0], stile, sh);
            else       stage_half(Ab, &As[stile & 1][0], stile, sh);
          }
        }
        __builtin_amdgcn_sched_barrier(0);
        __builtin_amdgcn_s_barrier();
        asm volatile("s_waitcnt lgkmcnt(0)" ::: "memory");
        __builtin_amdgcn_sched_barrier(0);
        __builtin_amdgcn_s_setprio(1);
        #pragma unroll
        for (int kc = 0; kc < 2; ++kc)
          #pragma unroll
          for (int i = 0; i < 4; ++i)
            #pragma unroll
            for (int j = 0; j < 2; ++j)
              acc[rm * 4 + i][cn * 2 + j] =
                  __builtin_amdgcn_mfma_f32_16x16x32_bf16(
                      a[kc][i], b[kc][cn][j], acc[rm * 4 + i][cn * 2 + j],
                      0, 0, 0);
        __builtin_amdgcn_s_setprio(0);
        if (p == 3) {
          if (u == 0) {
            if (tt + 2 < nk) asm volatile("s_waitcnt vmcnt(4)" ::: "memory");
            else             asm volatile("s_waitcnt vmcnt(0)" ::: "memory");
          } else {
            if (tt + 2 < nk) asm volatile("s_waitcnt vmcnt(4)" ::: "memory");
          }
        }
        __builtin_amdgcn_s_barrier();
      }
    }
  }

  bf16* Cb = C + (long)bz * sCz;
  #pragma unroll
  for (int rm = 0; rm < 2; ++rm)
    #pragma unroll
    for (int i = 0; i < 4; ++i) {
      const int row = by * 256 + rm * 128 + wr * 64 + i * 16 + quad * 4;
      #pragma unroll
      for (int cn = 0; cn < 2; ++cn)
        #pragma unroll
        for (int j = 0; j < 2; ++j) {
          const int col = bx * 256 + cn * 128 + wc * 32 + j * 16 + l16;
          floatx4 v = acc[rm * 4 + i][cn * 2 + j];
          #pragma unroll
          for (int r = 0; r < 4; ++r)
            Cb[(long)(row + r) * ldc + col] = __float2bfloat16(v[r] * scale);
        }
    }
}

// ---------------------------------------------------------------------------
// fused_smpv v5: softmax + PV; V direct from L2; AGE-GUARANTEED pipeline.
// v4's bug: the Sim load consumed by writeA was the NEWEST vm-op, so its
// wait retired the V prefetch (vmcnt queue is strictly ordered). v5 fixes
// this structurally: Sim loads are pipelined 2 chunks deep (unEven/unOdd),
// so every writeA consumes a load issued >= 1 full chunk earlier — strictly
// OLDER than all in-flight V loads. All waits are counted (vmcnt(9-10)),
// never 0, independent of compiler instruction order. Barriers drain only
// lgkmcnt (P ds_writes); V loads legally stay in flight across them.
// LDS = Apv (P) double-buffer only, 16.6 KB.
// ---------------------------------------------------------------------------
__global__ __launch_bounds__(512, 2) void fused_smpv(
    const bf16* __restrict__ Sim, const bf16* __restrict__ Vt,
    bf16* __restrict__ Ob) {
  __shared__ __align__(16) bf16 Apv[2][64 * 64];    // P chunk (8KB each)
  __shared__ float rl_lds[64];

  const int id = blockIdx.x + (blockIdx.y << 6);    // 0..255
  const int xcd = id & 7;
  const int bz = xcd >> 1;                          // 2 XCDs per batch
  const int by = ((id >> 3) << 1) | (id & 1);       // q row-tile 0..63

  const int tid = threadIdx.x;
  const bf16* Simb = Sim + (long)bz * ((long)SEQ * SEQ) + (long)(by * 64) * SEQ;
  const bf16* Vb   = Vt  + (long)bz * ((long)SEQ * CH);
  bf16* Obb        = Ob  + (long)bz * ((long)SEQ * CH) + (long)(by * 64) * CH;

  const int srow = tid >> 3;        // 0..63: P row this thread stages
  const int sp = tid & 7;           // 16B slot
  const int aswz = (sp ^ (srow & 7)) << 4;   // swizzled LDS byte slot

  const int w = tid >> 6, lane = tid & 63;
  const int l16 = lane & 15, quad = lane >> 4;
  const int pA0 = (quad ^ (l16 & 7)) << 3;
  const int pA1 = pA0 ^ 32;

  // per-lane V base: row (w*64 + l16), k-offset quad*8 within each chunk
  const bf16* Vw = Vb + (long)(w * 64 + l16) * SEQ + quad * 8;

  float lsum = 0.f;  // partial exp-sum for row srow

  auto writeA = [&](int buf, uint4 u) {
    const ushort* h = (const ushort*)&u;
    union { uint4 u4; ushort hh[8]; } pk;
    #pragma unroll
    for (int k2 = 0; k2 < 8; ++k2) {
      float f = __uint_as_float(((unsigned)h[k2]) << 16);
      float e = hw_exp2(f);          // P = 2^(s*log2e) = e^s
      lsum += e;
      __hip_bfloat16 pb = __float2bfloat16(e);
      pk.hh[k2] = *(const ushort*)&pb;
    }
    *(uint4*)((char*)(&Apv[buf][0]) + srow * 128 + aswz) = pk.u4;
  };

  short8 bA[2][4], bB[2][4];
  auto loadV = [&](short8 (&dst)[2][4], int t) {
    #pragma unroll
    for (int j = 0; j < 4; ++j) {
      const bf16* p = Vw + (long)(j * 16) * SEQ + t * 64;
      dst[0][j] = *(const short8*)(p);
      dst[1][j] = *(const short8*)(p + 32);
    }
  };
  auto loadSim = [&](int t) {
    return *(const uint4*)(Simb + (long)srow * SEQ + t * 64 + sp * 8);
  };

  // ---- prologue ----
  uint4 un0 = loadSim(0);      // consumed immediately (cold, one-time)
  loadV(bA, 0);                // V chunk 0, outstanding through writeA
  uint4 unEven = loadSim(1);   // P source for chunk 1 (written end of chunk 0)
  uint4 unOdd;
  writeA(0, un0);              // waits un0 only (oldest); bA+unEven in flight
  asm volatile("s_waitcnt lgkmcnt(0)" ::: "memory");
  __builtin_amdgcn_s_barrier();
  __builtin_amdgcn_sched_barrier(0);

  floatx4 acc[4][4];
  #pragma unroll
  for (int i = 0; i < 4; ++i)
    #pragma unroll
    for (int j = 0; j < 4; ++j) acc[i][j] = (floatx4)(0.0f);

  const int nk = SEQ >> 6;  // 64 chunks, even
  for (int t = 0; t < nk; t += 2) {
    // ===== even chunk t: P in Apv[0], V in bA =====
    {
      loadV(bB, t + 1);                       // t+1 <= 63 always
      if (t + 2 < nk) unOdd = loadSim(t + 2); // consumed end of odd chunk
      short8 a[2][4];
      #pragma unroll
      for (int kc = 0; kc < 2; ++kc) {
        const int poff = kc ? pA1 : pA0;
        #pragma unroll
        for (int i = 0; i < 4; ++i)
          a[kc][i] = *(const short8*)(&Apv[0][0] + (i * 16 + l16) * 64 + poff);
      }
      __builtin_amdgcn_s_setprio(1);
      #pragma unroll
      for (int kc = 0; kc < 2; ++kc)
        #pragma unroll
        for (int i = 0; i < 4; ++i)
          #pragma unroll
          for (int j = 0; j < 4; ++j)
            acc[i][j] = __builtin_amdgcn_mfma_f32_16x16x32_bf16(
                a[kc][i], bA[kc][j], acc[i][j], 0, 0, 0);
      __builtin_amdgcn_s_setprio(0);
      writeA(1, unEven);                      // unEven issued >=1 chunk ago
      asm volatile("s_waitcnt lgkmcnt(0)" ::: "memory");
      __builtin_amdgcn_s_barrier();
      __builtin_amdgcn_sched_barrier(0);
    }
    // ===== odd chunk t+1: P in Apv[1], V in bB =====
    {
      const bool more = (t + 2 < nk);
      if (more) {
        loadV(bA, t + 2);
        if (t + 3 < nk) unEven = loadSim(t + 3);
      }
      short8 a[2][4];
      #pragma unroll
      for (int kc = 0; kc < 2; ++kc) {
        const int poff = kc ? pA1 : pA0;
        #pragma unroll
        for (int i = 0; i < 4; ++i)
          a[kc][i] = *(const short8*)(&Apv[1][0] + (i * 16 + l16) * 64 + poff);
      }
      __builtin_amdgcn_s_setprio(1);
      #pragma unroll
      for (int kc = 0; kc < 2; ++kc)
        #pragma unroll
        for (int i = 0; i < 4; ++i)
          #pragma unroll
          for (int j = 0; j < 4; ++j)
            acc[i][j] = __builtin_amdgcn_mfma_f32_16x16x32_bf16(
                a[kc][i], bB[kc][j], acc[i][j], 0, 0, 0);
      __builtin_amdgcn_s_setprio(0);
      if (more) {
        writeA(0, unOdd);                     // unOdd issued 1.5 chunks ago
        asm volatile("s_waitcnt lgkmcnt(0)" ::: "memory");
        __builtin_amdgcn_s_barrier();
        __builtin_amdgcn_sched_barrier(0);
      }
    }
  }

  // ---- row exp-sum reduce (8 lanes per row are contiguous in-wave) ----
  #pragma unroll
  for (int o = 1; o < 8; o <<= 1) lsum += __shfl_xor(lsum, o);
  if (sp == 0) rl_lds[srow] = 1.0f / lsum;
  __syncthreads();

  // ---- epilogue: O * (1/l), bf16, row-major [s][d] ----
  #pragma unroll
  for (int i = 0; i < 4; ++i) {
    #pragma unroll
    for (int j = 0; j < 4; ++j) {
      floatx4 v = acc[i][j];
      const int col = w * 64 + j * 16 + l16;
      #pragma unroll
      for (int r = 0; r < 4; ++r) {
        const int row = i * 16 + quad * 4 + r;
        Obb[(long)row * CH + col] = __float2bfloat16(v[r] * rl_lds[row]);
      }
    }
  }
}

// ---------------------------------------------------------------------------
extern "C" void kernel_launch(void* const* d_in, const int* in_sizes, int n_in,
                              void* d_out, int out_size, void* d_ws,
                              size_t ws_size, hipStream_t stream) {
  const float* q  = (const float*)d_in[0];
  const float* Wq = (const float*)d_in[1];
  const float* bq = (const float*)d_in[2];
  const float* Wk = (const float*)d_in[3];
  const float* bk = (const float*)d_in[4];
  const float* Wv = (const float*)d_in[5];
  const float* bv = (const float*)d_in[6];
  const float* Wo = (const float*)d_in[7];
  const float* bo = (const float*)d_in[8];
  float* out = (float*)d_out;

  bf16* ws = (bf16*)d_ws;
  const long WSZ = (long)DM * CH;         // 262144 elems per weight matrix
  const long XSZ = (long)SEQ * CH;        // 2097152 elems per batch
  const long SSZ = (long)SEQ * SEQ;       // 16777216 elems per batch
  bf16* Wqb = ws;                          // Wq,Wk,Wv,Wo contiguous
  bf16* Wob = Wqb + 3 * WSZ;
  bf16* xT  = Wqb + 4 * WSZ;
  bf16* Qb  = xT + BATCH * XSZ;            // Q,K,Vt contiguous (proj128 kind 0)
  bf16* Kb  = Qb + BATCH * XSZ;
  bf16* Vt  = Kb + BATCH * XSZ;   // (b, d, s) layout
  bf16* Ob  = Vt + BATCH * XSZ;
  bf16* Sim = Ob + BATCH * XSZ;   // (b, s, t) bf16, pre-scaled by log2e

  cvt_weights<<<dim3(WSZ / 256, 4), 256, 0, stream>>>(Wq, Wk, Wv, Wo, ws);
  transpose_cvt<<<dim3(SEQ / 64, CH / 64, BATCH), 256, 0, stream>>>(q, xT);

  // Q,K,V projections fused into one launch (z = mat*4 + batch)
  proj128<0><<<dim3(4, 32, 12), 256, 0, stream>>>(
      xT, Wqb, bq, bk, bv, Qb);
  // sim = Q*K^T * (scale*log2e) (4096x4096x512)
  const float qkscale = 0.04419417382415922f * 1.4426950408889634f;
  gemm_qk<<<dim3(16, 16, BATCH), 512, 0, stream>>>(
      Qb, XSZ, Kb, XSZ, Sim, SSZ, qkscale, CH, SEQ);
  // o = softmax(sim) * V, single-pass fused, V direct + age-guaranteed pipe
  fused_smpv<<<dim3(64, 4), 512, 0, stream>>>(Sim, Vt, Ob);
  // y = o * Wo^T + bo, stored transposed into d_out as (b, c, s) fp32
  proj128<1><<<dim3(4, 32, 4), 256, 0, stream>>>(
      Ob, Wob, bo, nullptr, nullptr, out);
}

// Round 15
// 344.275 us; speedup vs baseline: 1.1011x; 1.1011x over previous
//
#include <hip/hip_runtime.h>
#include <hip/hip_bf16.h>

typedef __hip_bfloat16 bf16;
typedef __attribute__((ext_vector_type(8))) short short8;
typedef __attribute__((ext_vector_type(4))) float floatx4;
typedef __attribute__((ext_vector_type(4))) short shortx4;

static constexpr int BATCH = 4;
static constexpr int CH    = 512;   // C
static constexpr int SEQ   = 4096;  // H*W
static constexpr int DM    = 512;   // model dim

__device__ __forceinline__ void gload16(const void* g, void* l) {
  __builtin_amdgcn_global_load_lds(
      (const __attribute__((address_space(1))) unsigned int*)g,
      (__attribute__((address_space(3))) unsigned int*)l,
      16, 0, 0);
}

// 2^x via the hardware transcendental (avoids glibc __exp2f macro collision)
__device__ __forceinline__ float hw_exp2(float x) {
  float r;
  asm("v_exp_f32 %0, %1" : "=v"(r) : "v"(x));
  return r;
}

// ---------------------------------------------------------------------------
// Weight fp32 -> bf16 conversion (4 matrices of 512x512)
// ---------------------------------------------------------------------------
__global__ __launch_bounds__(256) void cvt_weights(
    const float* __restrict__ w0, const float* __restrict__ w1,
    const float* __restrict__ w2, const float* __restrict__ w3,
    bf16* __restrict__ out) {
  const float* src = (blockIdx.y == 0) ? w0 : (blockIdx.y == 1) ? w1
                   : (blockIdx.y == 2) ? w2 : w3;
  int idx = blockIdx.x * 256 + threadIdx.x;
  out[(long)blockIdx.y * (DM * CH) + idx] = __float2bfloat16(src[idx]);
}

// ---------------------------------------------------------------------------
// x (b,c,s) fp32 -> xT (b,s,c) bf16, 64x64 LDS tiles
// ---------------------------------------------------------------------------
__global__ __launch_bounds__(256) void transpose_cvt(
    const float* __restrict__ x, bf16* __restrict__ xT) {
  __shared__ float tile[64][65];
  const int s0 = blockIdx.x * 64, c0 = blockIdx.y * 64;
  const float* xb = x + (long)blockIdx.z * CH * SEQ;
  bf16* xTb = xT + (long)blockIdx.z * SEQ * CH;
  const int t = threadIdx.x;
  const int sl = t & 63, cq = t >> 6;
  #pragma unroll
  for (int i = 0; i < 16; ++i) {
    int cl = cq * 16 + i;
    tile[cl][sl] = xb[(long)(c0 + cl) * SEQ + s0 + sl];
  }
  __syncthreads();
  const int cl2 = t & 63, sq = t >> 6;
  #pragma unroll
  for (int i = 0; i < 16; ++i) {
    int sl2 = sq * 16 + i;
    xTb[(long)(s0 + sl2) * CH + c0 + cl2] = __float2bfloat16(tile[cl2][sl2]);
  }
}

// ---------------------------------------------------------------------------
// proj128: 128x128 tile BT-GEMM for the K=512 projections. 256 threads,
// 4 waves (2x2, per-wave 64x64), BK=64, double-buffered, 64 KB LDS ->
// 2 blocks/CU (cross-block overlap hides the per-tile drain).
// KIND 0: QKV fused. grid.z = mat*4+batch (12). mat 0/1 -> bf16 row-major
//   [s][d] + bias; mat 2 -> bf16 transposed [d][s] + bias.
// KIND 1: out-proj. grid.z = batch (4). fp32 transposed [c][s] + bias.
// ---------------------------------------------------------------------------
template <int KIND>
__global__ __launch_bounds__(256, 2) void proj128(
    const bf16* __restrict__ A0, const bf16* __restrict__ Wbase,
    const float* __restrict__ b0, const float* __restrict__ b1,
    const float* __restrict__ b2, void* __restrict__ Cbase) {
  __shared__ __align__(16) bf16 As[2][128 * 64];
  __shared__ __align__(16) bf16 Bs[2][128 * 64];

  int id = blockIdx.x + gridDim.x * (blockIdx.y + gridDim.y * blockIdx.z);
  int nwg = gridDim.x * gridDim.y * gridDim.z;
  int sid = ((nwg & 7) == 0) ? ((id & 7) * (nwg >> 3) + (id >> 3)) : id;
  const int bx = sid % gridDim.x;
  const int by = (sid / gridDim.x) % gridDim.y;
  const int z  = sid / (gridDim.x * gridDim.y);
  const int mat = (KIND == 0) ? (z >> 2) : 0;
  const int bz  = (KIND == 0) ? (z & 3) : z;

  const long XSZ = (long)SEQ * CH;
  const long lK = CH;
  const bf16* Ab = A0 + (long)bz * XSZ + (long)by * 128 * lK;
  const bf16* Bb = Wbase + (long)mat * ((long)DM * CH) + (long)bx * 128 * lK;
  const float* bias = (KIND == 1) ? b0 : (mat == 0 ? b0 : mat == 1 ? b1 : b2);

  const int tid = threadIdx.x;
  const int w = tid >> 6, lane = tid & 63;
  const int wr = w >> 1, wc = w & 1;          // 2 x 2 wave grid
  const int l16 = lane & 15, quad = lane >> 4;
  const int srow = tid >> 3;                  // 0..31
  const int sp = tid & 7;
  const int slog = (sp ^ (srow & 7)) << 3;    // pre-swizzled source column
  const int pA0 = (quad ^ (l16 & 7)) << 3;
  const int pA1 = pA0 ^ 32;

  auto stageA = [&](int buf, int kt) {
    const bf16* s = Ab + kt * 64 + (long)srow * lK + slog;
    char* d = (char*)(&As[buf][0]) + tid * 16;
    #pragma unroll
    for (int r = 0; r < 4; ++r)
      gload16(s + (long)(r * 32) * lK, d + r * 4096);
  };
  auto stageB = [&](int buf, int kt) {
    const bf16* s = Bb + kt * 64 + (long)srow * lK + slog;
    char* d = (char*)(&Bs[buf][0]) + tid * 16;
    #pragma unroll
    for (int r = 0; r < 4; ++r)
      gload16(s + (long)(r * 32) * lK, d + r * 4096);
  };

  floatx4 acc[4][4];
  #pragma unroll
  for (int m = 0; m < 4; ++m)
    #pragma unroll
    for (int n = 0; n < 4; ++n) acc[m][n] = (floatx4)(0.0f);

  const int nk = CH >> 6;  // 8
  stageA(0, 0); stageB(0, 0);
  __syncthreads();

  for (int t = 0; t < nk; ++t) {
    const int cur = t & 1, nxt = cur ^ 1;
    const bool more = (t + 1 < nk);
    #pragma unroll
    for (int kc = 0; kc < 2; ++kc) {
      const int poff = kc ? pA1 : pA0;
      short8 a[4], b[4];
      #pragma unroll
      for (int i = 0; i < 4; ++i)
        a[i] = *(const short8*)(&As[cur][0] + (wr * 64 + i * 16 + l16) * 64 + poff);
      #pragma unroll
      for (int j = 0; j < 4; ++j)
        b[j] = *(const short8*)(&Bs[cur][0] + (wc * 64 + j * 16 + l16) * 64 + poff);
      if (more) {
        if (kc == 0) stageA(nxt, t + 1);
        else         stageB(nxt, t + 1);
      }
      __builtin_amdgcn_s_setprio(1);
      #pragma unroll
      for (int i = 0; i < 4; ++i)
        #pragma unroll
        for (int j = 0; j < 4; ++j)
          acc[i][j] = __builtin_amdgcn_mfma_f32_16x16x32_bf16(
              a[i], b[j], acc[i][j], 0, 0, 0);
      __builtin_amdgcn_s_setprio(0);
    }
    __syncthreads();  // drains vm+lgkm; buffer swap safe
  }

  const int rbase = by * 128 + wr * 64 + quad * 4;
  const int cbase = bx * 128 + wc * 64 + l16;
  #pragma unroll
  for (int m = 0; m < 4; ++m) {
    const int row = rbase + m * 16;
    #pragma unroll
    for (int n = 0; n < 4; ++n) {
      const int col = cbase + n * 16;
      floatx4 v = acc[m][n];
      const float bb = bias[col];
      if constexpr (KIND == 0) {
        if (mat < 2) {
          bf16* C = (bf16*)Cbase + (long)mat * (BATCH * XSZ) + (long)bz * XSZ;
          #pragma unroll
          for (int r = 0; r < 4; ++r)
            C[(long)(row + r) * DM + col] = __float2bfloat16(v[r] + bb);
        } else {
          bf16* C = (bf16*)Cbase + 2 * (BATCH * XSZ) + (long)bz * XSZ;
          alignas(8) bf16 tmp[4];
          #pragma unroll
          for (int r = 0; r < 4; ++r) tmp[r] = __float2bfloat16(v[r] + bb);
          *(shortx4*)(C + (long)col * SEQ + row) = *(const shortx4*)tmp;
        }
      } else {
        float* C = (float*)Cbase + (long)bz * XSZ;
        floatx4 o_;
        #pragma unroll
        for (int r = 0; r < 4; ++r) o_[r] = v[r] + bb;
        *(floatx4*)(C + (long)col * SEQ + row) = o_;
      }
    }
  }
}

// ---------------------------------------------------------------------------
// gemm_qk: 256x256 tile QK^T. Output PRE-SCALED by scale*log2(e) so the
// downstream softmax uses exp2 directly.
// ---------------------------------------------------------------------------
__global__ __launch_bounds__(512, 2) void gemm_qk(
    const bf16* __restrict__ A, long sAz,
    const bf16* __restrict__ B, long sBz,
    bf16* __restrict__ C, long sCz,
    float scale, int K, int ldc) {
  __shared__ __align__(16) bf16 As[2][256 * 64];
  __shared__ __align__(16) bf16 Bs[2][256 * 64];

  int id = blockIdx.x + gridDim.x * (blockIdx.y + gridDim.y * blockIdx.z);
  int nwg = gridDim.x * gridDim.y * gridDim.z;
  int sid = ((nwg & 7) == 0) ? ((id & 7) * (nwg >> 3) + (id >> 3)) : id;
  const int bx = sid % gridDim.x;
  const int by = (sid / gridDim.x) % gridDim.y;
  const int bz = sid / (gridDim.x * gridDim.y);

  const int tid = threadIdx.x;
  const long lK = K;
  const bf16* Ab = A + (long)bz * sAz + (long)by * 256 * lK;
  const bf16* Bb = B + (long)bz * sBz + (long)bx * 256 * lK;

  const int w = tid >> 6, lane = tid & 63;
  const int wr = w >> 2, wc = w & 3;          // 2 x 4 wave grid
  const int l16 = lane & 15, quad = lane >> 4;

  const int srow = tid >> 3;                  // 0..63
  const int sp = tid & 7;                     // physical 16B slot
  const int slog = (sp ^ (srow & 7)) << 3;    // pre-swizzled source column

  const int pA0 = (quad ^ (l16 & 7)) << 3;
  const int pA1 = pA0 ^ 32;

  auto stage_half = [&](const bf16* Gb, bf16* Lb, int kt, int h) {
    #pragma unroll
    for (int r = 0; r < 2; ++r) {
      const int row = h * 128 + r * 64 + srow;
      gload16(Gb + (long)kt * 64 + (long)row * lK + slog,
              (char*)Lb + row * 128 + sp * 16);
    }
  };

  floatx4 acc[8][4];
  #pragma unroll
  for (int m = 0; m < 8; ++m)
    #pragma unroll
    for (int n = 0; n < 4; ++n) acc[m][n] = (floatx4)(0.0f);

  const int nk = K >> 6;  // even
  stage_half(Ab, &As[0][0], 0, 0); stage_half(Bb, &Bs[0][0], 0, 0);
  stage_half(Ab, &As[0][0], 0, 1); stage_half(Bb, &Bs[0][0], 0, 1);
  if (nk > 1) { stage_half(Ab, &As[1][0], 1, 0); stage_half(Bb, &Bs[1][0], 1, 0); }
  asm volatile("s_waitcnt vmcnt(4)" ::: "memory");
  __builtin_amdgcn_s_barrier();

  for (int tt = 0; tt < nk; tt += 2) {
    #pragma unroll
    for (int u = 0; u < 2; ++u) {
      const bf16* __restrict__ Al = &As[u][0];
      const bf16* __restrict__ Bl = &Bs[u][0];
      short8 a[2][4], b[2][2][2];
      #pragma unroll
      for (int p = 0; p < 4; ++p) {
        const int rm = p >> 1, cn = p & 1;
        if (cn == 0) {
          #pragma unroll
          for (int kc = 0; kc < 2; ++kc)
            #pragma unroll
            for (int i = 0; i < 4; ++i)
              a[kc][i] = *(const short8*)(
                  Al + (rm * 128 + wr * 64 + i * 16 + l16) * 64
                     + (kc ? pA1 : pA0));
        }
        if (rm == 0) {
          #pragma unroll
          for (int kc = 0; kc < 2; ++kc)
            #pragma unroll
            for (int j = 0; j < 2; ++j)
              b[kc][cn][j] = *(const short8*)(
                  Bl + (cn * 128 + wc * 32 + j * 16 + l16) * 64
                     + (kc ? pA1 : pA0));
        }
        {
          const int g = u * 4 + p;
          const int stile = tt + 1 + ((g + 2) >> 2);
          if (stile < nk) {
            const int sh = (p < 2) ? 1 : 0;
            if (p & 1) stage_half(Bb, &Bs[stile & 1][0], stile, sh);
            else       stage_half(Ab, &As[stile & 1][0], stile, sh);
          }
        }
        __builtin_amdgcn_sched_barrier(0);
        __builtin_amdgcn_s_barrier();
        asm volatile("s_waitcnt lgkmcnt(0)" ::: "memory");
        __builtin_amdgcn_sched_barrier(0);
        __builtin_amdgcn_s_setprio(1);
        #pragma unroll
        for (int kc = 0; kc < 2; ++kc)
          #pragma unroll
          for (int i = 0; i < 4; ++i)
            #pragma unroll
            for (int j = 0; j < 2; ++j)
              acc[rm * 4 + i][cn * 2 + j] =
                  __builtin_amdgcn_mfma_f32_16x16x32_bf16(
                      a[kc][i], b[kc][cn][j], acc[rm * 4 + i][cn * 2 + j],
                      0, 0, 0);
        __builtin_amdgcn_s_setprio(0);
        if (p == 3) {
          if (u == 0) {
            if (tt + 2 < nk) asm volatile("s_waitcnt vmcnt(4)" ::: "memory");
            else             asm volatile("s_waitcnt vmcnt(0)" ::: "memory");
          } else {
            if (tt + 2 < nk) asm volatile("s_waitcnt vmcnt(4)" ::: "memory");
          }
        }
        __builtin_amdgcn_s_barrier();
      }
    }
  }

  bf16* Cb = C + (long)bz * sCz;
  #pragma unroll
  for (int rm = 0; rm < 2; ++rm)
    #pragma unroll
    for (int i = 0; i < 4; ++i) {
      const int row = by * 256 + rm * 128 + wr * 64 + i * 16 + quad * 4;
      #pragma unroll
      for (int cn = 0; cn < 2; ++cn)
        #pragma unroll
        for (int j = 0; j < 2; ++j) {
          const int col = bx * 256 + cn * 128 + wc * 32 + j * 16 + l16;
          floatx4 v = acc[rm * 4 + i][cn * 2 + j];
          #pragma unroll
          for (int r = 0; r < 4; ++r)
            Cb[(long)(row + r) * ldc + col] = __float2bfloat16(v[r] * scale);
        }
    }
}

// ---------------------------------------------------------------------------
// fused_smpv v6: v2's data path (gload_lds V staging + LDS P) at 2 blocks/CU.
// BM=32 q-rows, KVBLK=64, SINGLE-buffered Apv (4 KB) + Bpv (64 KB) = 68.4 KB
// -> 2 blocks/CU (grid 512). Single buffers are race-free by construction:
//   frag reads -> lgkmcnt(0)+barrier -> overwrite (stageB8 / writeA) ->
//   __syncthreads (drains V gloads + P writes).
// The Sim load is issued BEFORE barrier1 (memory clobber pins it) -> older
// than the V gloads -> writeA's wait leaves V in flight (counted by order).
// Cross-block TLP (m114, proj128's mechanism) hides the per-chunk stall that
// capped v2 at 25% MfmaUtil. Cost: V staged 2x more often per unit work.
// ---------------------------------------------------------------------------
__global__ __launch_bounds__(512, 4) void fused_smpv(
    const bf16* __restrict__ Sim, const bf16* __restrict__ Vt,
    bf16* __restrict__ Ob) {
  __shared__ __align__(16) bf16 Apv[32 * 64];     // P chunk, 4 KB, single
  __shared__ __align__(16) bf16 Bpv[512 * 64];    // V chunk, 64 KB, single
  __shared__ float rl_lds[32];

  const int id = blockIdx.x + (blockIdx.y << 7);  // grid (128,4) -> 0..511
  const int xcd = id & 7;
  const int bz = xcd >> 1;                        // 2 XCDs per batch
  const int by = ((id >> 3) << 1) | (id & 1);     // q row-tile 0..127

  const int tid = threadIdx.x;
  const bf16* Simb = Sim + (long)bz * ((long)SEQ * SEQ) + (long)(by * 32) * SEQ;
  const bf16* Vb   = Vt  + (long)bz * ((long)SEQ * CH);
  bf16* Obb        = Ob  + (long)bz * ((long)SEQ * CH) + (long)(by * 32) * CH;

  // P staging: row = tid>>4 (0..31), 4 cols (8 B) per thread
  const int prow = tid >> 4;
  const int pcol = (tid & 15) * 4;
  const int pwbyte = prow * 128 + (((pcol >> 3) ^ (prow & 7)) << 4)
                   + ((pcol & 7) << 1);

  // V staging: srow = tid>>3 (0..63), 16B slot sp, pre-swizzled source
  const int srow = tid >> 3;
  const int sp = tid & 7;
  const int slog = (sp ^ (srow & 7)) << 3;

  const int w = tid >> 6, lane = tid & 63;
  const int l16 = lane & 15, quad = lane >> 4;
  const int pA0 = (quad ^ (l16 & 7)) << 3;
  const int pA1 = pA0 ^ 32;

  float lsum = 0.f;  // partial exp-sum for row prow (16 threads/row)

  auto stageB8 = [&](int kt) {
    const bf16* s = Vb + (long)srow * SEQ + kt * 64 + slog;
    char* d = (char*)Bpv + tid * 16;
    #pragma unroll
    for (int r = 0; r < 8; ++r)
      gload16(s + (long)(r * 64) * SEQ, d + r * 8192);
  };
  auto loadSim = [&](int t) {
    return *(const uint2*)(Simb + (long)prow * SEQ + t * 64 + pcol);
  };
  auto writeA = [&](uint2 u) {
    const ushort* h = (const ushort*)&u;
    union { uint2 u2; ushort hh[4]; } pk;
    #pragma unroll
    for (int k2 = 0; k2 < 4; ++k2) {
      float f = __uint_as_float(((unsigned)h[k2]) << 16);
      float e = hw_exp2(f);          // P = 2^(s*log2e) = e^s
      lsum += e;
      __hip_bfloat16 pb = __float2bfloat16(e);
      pk.hh[k2] = *(const ushort*)&pb;
    }
    *(uint2*)((char*)Apv + pwbyte) = pk.u2;
  };

  // ---- prologue: chunk 0 ----
  stageB8(0);
  writeA(loadSim(0));
  __syncthreads();   // V(0) landed, P(0) written

  floatx4 acc[2][4];
  #pragma unroll
  for (int i = 0; i < 2; ++i)
    #pragma unroll
    for (int j = 0; j < 4; ++j) acc[i][j] = (floatx4)(0.0f);

  const int nk = SEQ >> 6;  // 64 chunks
  for (int t = 0; t < nk; ++t) {
    const bool more = (t + 1 < nk);
    uint2 un;
    if (more) un = loadSim(t + 1);   // issued before barrier1 -> older than V
    short8 a[2][2], b[2][4];
    #pragma unroll
    for (int kc = 0; kc < 2; ++kc) {
      const int poff = kc ? pA1 : pA0;
      #pragma unroll
      for (int i = 0; i < 2; ++i)
        a[kc][i] = *(const short8*)(Apv + (i * 16 + l16) * 64 + poff);
      #pragma unroll
      for (int j = 0; j < 4; ++j)
        b[kc][j] = *(const short8*)(Bpv + (w * 64 + j * 16 + l16) * 64 + poff);
    }
    // all LDS reads in regs block-wide; then safe to overwrite
    asm volatile("s_waitcnt lgkmcnt(0)" ::: "memory");
    __builtin_amdgcn_s_barrier();
    __builtin_amdgcn_sched_barrier(0);
    if (more) stageB8(t + 1);        // overwrite Bpv
    __builtin_amdgcn_s_setprio(1);
    #pragma unroll
    for (int kc = 0; kc < 2; ++kc)
      #pragma unroll
      for (int i = 0; i < 2; ++i)
        #pragma unroll
        for (int j = 0; j < 4; ++j)
          acc[i][j] = __builtin_amdgcn_mfma_f32_16x16x32_bf16(
              a[kc][i], b[kc][j], acc[i][j], 0, 0, 0);
    __builtin_amdgcn_s_setprio(0);
    if (more) writeA(un);            // overwrite Apv (waits un only: older)
    __syncthreads();                 // V(t+1) landed + P(t+1) written
  }

  // ---- row exp-sum reduce (16 threads per row, contiguous in-wave) ----
  #pragma unroll
  for (int o = 1; o < 16; o <<= 1) lsum += __shfl_xor(lsum, o);
  if ((tid & 15) == 0) rl_lds[prow] = 1.0f / lsum;
  __syncthreads();

  // ---- epilogue: O * (1/l), bf16, row-major [s][d] ----
  #pragma unroll
  for (int i = 0; i < 2; ++i) {
    #pragma unroll
    for (int j = 0; j < 4; ++j) {
      floatx4 v = acc[i][j];
      const int col = w * 64 + j * 16 + l16;
      #pragma unroll
      for (int r = 0; r < 4; ++r) {
        const int row = i * 16 + quad * 4 + r;
        Obb[(long)row * CH + col] = __float2bfloat16(v[r] * rl_lds[row]);
      }
    }
  }
}

// ---------------------------------------------------------------------------
extern "C" void kernel_launch(void* const* d_in, const int* in_sizes, int n_in,
                              void* d_out, int out_size, void* d_ws,
                              size_t ws_size, hipStream_t stream) {
  const float* q  = (const float*)d_in[0];
  const float* Wq = (const float*)d_in[1];
  const float* bq = (const float*)d_in[2];
  const float* Wk = (const float*)d_in[3];
  const float* bk = (const float*)d_in[4];
  const float* Wv = (const float*)d_in[5];
  const float* bv = (const float*)d_in[6];
  const float* Wo = (const float*)d_in[7];
  const float* bo = (const float*)d_in[8];
  float* out = (float*)d_out;

  bf16* ws = (bf16*)d_ws;
  const long WSZ = (long)DM * CH;         // 262144 elems per weight matrix
  const long XSZ = (long)SEQ * CH;        // 2097152 elems per batch
  const long SSZ = (long)SEQ * SEQ;       // 16777216 elems per batch
  bf16* Wqb = ws;                          // Wq,Wk,Wv,Wo contiguous
  bf16* Wob = Wqb + 3 * WSZ;
  bf16* xT  = Wqb + 4 * WSZ;
  bf16* Qb  = xT + BATCH * XSZ;            // Q,K,Vt contiguous (proj128 kind 0)
  bf16* Kb  = Qb + BATCH * XSZ;
  bf16* Vt  = Kb + BATCH * XSZ;   // (b, d, s) layout
  bf16* Ob  = Vt + BATCH * XSZ;
  bf16* Sim = Ob + BATCH * XSZ;   // (b, s, t) bf16, pre-scaled by log2e

  cvt_weights<<<dim3(WSZ / 256, 4), 256, 0, stream>>>(Wq, Wk, Wv, Wo, ws);
  transpose_cvt<<<dim3(SEQ / 64, CH / 64, BATCH), 256, 0, stream>>>(q, xT);

  // Q,K,V projections fused into one launch (z = mat*4 + batch)
  proj128<0><<<dim3(4, 32, 12), 256, 0, stream>>>(
      xT, Wqb, bq, bk, bv, Qb);
  // sim = Q*K^T * (scale*log2e) (4096x4096x512)
  const float qkscale = 0.04419417382415922f * 1.4426950408889634f;
  gemm_qk<<<dim3(16, 16, BATCH), 512, 0, stream>>>(
      Qb, XSZ, Kb, XSZ, Sim, SSZ, qkscale, CH, SEQ);
  // o = softmax(sim) * V, single-pass fused, 2 blocks/CU
  fused_smpv<<<dim3(128, 4), 512, 0, stream>>>(Sim, Vt, Ob);
  // y = o * Wo^T + bo, stored transposed into d_out as (b, c, s) fp32
  proj128<1><<<dim3(4, 32, 4), 256, 0, stream>>>(
      Ob, Wob, bo, nullptr, nullptr, out);
}